// Round 10
// baseline (14819.759 us; speedup 1.0000x reference)
//
#include <hip/hip_runtime.h>
#include <hip/hip_bf16.h>

// AWQ w4a16 GEMM + fused LoRA, MI355X (gfx950).
//   Xe  [8192][4160] bf16 = [ x (bf16) | t = x @ lora_a (bf16) ]
//   Wt  [11008][4160] bf16 = [ ((q - z) * s)^T | lora_b^T ]
//   out [8192][11008] f32 = Xe @ Wt^T     (K' = 4160, 130 K-tiles of 32)
// GEMM r10: 256x256 tile (FETCH stays 1.5GB), BK=32, 8 waves (2Mx4N, wave
// 128x64), 32x32x16 MFMA, LDS 64 KiB -> TWO blocks/CU co-resident. Simple
// 1-barrier-per-K-tile loop; the intra-block stall (barrier/lgkm/read
// serialization) overlaps with the sibling block's MFMAs (m114 mechanism).
// Swizzle for [256][32] layout: sigma(row)=row&3 both sides; verified even
// bank spread (floor-only). Grid 1376 = 8*172 bijective XCD swizzle.

typedef __bf16 bf16x8 __attribute__((ext_vector_type(8)));
typedef float f32x16 __attribute__((ext_vector_type(16)));

#define GLOAD_LDS16(gp, lp)                                                    \
  __builtin_amdgcn_global_load_lds(                                            \
      (const __attribute__((address_space(1))) void*)(gp),                     \
      (__attribute__((address_space(3))) void*)(lp), 16, 0, 0)

#define SB0() __builtin_amdgcn_sched_barrier(0)
#define BAR() __builtin_amdgcn_s_barrier()

__device__ __forceinline__ unsigned short f2b(float f) {
  unsigned int u = __builtin_bit_cast(unsigned int, f);
  unsigned int r = u + 0x7fffu + ((u >> 16) & 1u);  // RTNE
  return (unsigned short)(r >> 16);
}

constexpr int M_DIM = 8192;
constexpr int K_DIM = 4096;
constexpr int N_DIM = 11008;
constexpr int R_DIM = 64;
constexpr int KP = K_DIM + R_DIM;  // 4160
constexpr int NT32 = KP / 32;      // 130 K-tiles of 32

// ---------------------------------------------------------------- prep: t = x@A, plus x->bf16
__global__ __launch_bounds__(256) void prep_x_kernel(
    const float* __restrict__ x, const float* __restrict__ A,
    unsigned short* __restrict__ Xe) {
  __shared__ float xs[16][128];
  __shared__ float as[128][64];
  const int tid = threadIdx.x;
  const int r0 = blockIdx.x * 16;
  const int c = tid & 63;
  const int rg = tid >> 6;
  float acc[4] = {0.f, 0.f, 0.f, 0.f};
  for (int kc = 0; kc < K_DIM; kc += 128) {
    __syncthreads();
#pragma unroll
    for (int i = 0; i < 2; ++i) {
      const int flat = i * 1024 + tid * 4;
      const int row = flat >> 7, col = flat & 127;
      const float4 v = *(const float4*)(x + (size_t)(r0 + row) * K_DIM + kc + col);
      *(float4*)&xs[row][col] = v;
      unsigned short h[4] = {f2b(v.x), f2b(v.y), f2b(v.z), f2b(v.w)};
      *(uint2*)(Xe + (size_t)(r0 + row) * KP + kc + col) = *(const uint2*)h;
    }
#pragma unroll
    for (int j = 0; j < 8; ++j)
      ((float4*)as)[j * 256 + tid] =
          ((const float4*)(A + (size_t)kc * R_DIM))[j * 256 + tid];
    __syncthreads();
    for (int kk = 0; kk < 128; kk += 4) {
      float4 xv[4];
#pragma unroll
      for (int i = 0; i < 4; ++i) xv[i] = *(const float4*)&xs[rg * 4 + i][kk];
#pragma unroll
      for (int q = 0; q < 4; ++q) {
        const float b = as[kk + q][c];
        acc[0] += ((const float*)&xv[0])[q] * b;
        acc[1] += ((const float*)&xv[1])[q] * b;
        acc[2] += ((const float*)&xv[2])[q] * b;
        acc[3] += ((const float*)&xv[3])[q] * b;
      }
    }
  }
#pragma unroll
  for (int i = 0; i < 4; ++i)
    Xe[(size_t)(r0 + rg * 4 + i) * KP + K_DIM + c] = f2b(acc[i]);
}

// ---------------------------------------------------------------- prep: dequant + transpose
__global__ __launch_bounds__(256) void dequant_kernel(
    const int* __restrict__ qw, const int* __restrict__ qz,
    const float* __restrict__ sc, unsigned short* __restrict__ Wt) {
  __shared__ unsigned short w_lds[64][257];
  const int tid = threadIdx.x;
  const int n0 = blockIdx.x * 256, k0 = blockIdx.y * 64;
  const int g = k0 >> 7;  // 64-k tile never crosses a 128-k group
  const int nl = (tid & 63) * 4;
  const int kb = tid >> 6;
  const int4 zq = *(const int4*)(qz + (size_t)g * N_DIM + n0 + nl);
  const float4 sv = *(const float4*)(sc + (size_t)g * N_DIM + n0 + nl);
#pragma unroll
  for (int i = 0; i < 16; ++i) {
    const int kl = i * 4 + kb;
    const int4 q = *(const int4*)(qw + (size_t)(k0 + kl) * N_DIM + n0 + nl);
    w_lds[kl][nl + 0] = f2b((float)(q.x - zq.x) * sv.x);
    w_lds[kl][nl + 1] = f2b((float)(q.y - zq.y) * sv.y);
    w_lds[kl][nl + 2] = f2b((float)(q.z - zq.z) * sv.z);
    w_lds[kl][nl + 3] = f2b((float)(q.w - zq.w) * sv.w);
  }
  __syncthreads();
  const int c = tid & 7;         // k-chunk (8 k = 16B)
  const int ns = (tid >> 3) & 7; // n-sub within wave
  const int w = tid >> 6;
#pragma unroll
  for (int v = 0; v < 8; ++v) {
    const int n = w * 64 + v * 8 + ns;
    unsigned short tmp[8];
#pragma unroll
    for (int i = 0; i < 8; ++i) tmp[i] = w_lds[c * 8 + i][n];
    *(uint4*)(Wt + (size_t)(n0 + n) * KP + k0 + c * 8) = *(const uint4*)tmp;
  }
}

// ---------------------------------------------------------------- prep: lora_b^T
__global__ __launch_bounds__(256) void lorab_t_kernel(
    const float* __restrict__ B, unsigned short* __restrict__ Wt) {
  __shared__ unsigned short b_lds[64][68];
  const int tid = threadIdx.x;
  const int n0 = blockIdx.x * 64;
  const int nl = tid & 63;
  const int rl0 = tid >> 6;
#pragma unroll
  for (int i = 0; i < 16; ++i) {
    const int rl = i * 4 + rl0;
    b_lds[nl][rl] = f2b(B[(size_t)rl * N_DIM + n0 + nl]);
  }
  __syncthreads();
#pragma unroll
  for (int p = 0; p < 2; ++p) {
    const int chunk = p * 256 + tid;
    const int nr = chunk >> 3, r8 = chunk & 7;
    const unsigned short* rp = &b_lds[nr][r8 * 8];
    const uint2 lo = *(const uint2*)rp;
    const uint2 hi = *(const uint2*)(rp + 4);
    uint4 v;
    v.x = lo.x; v.y = lo.y; v.z = hi.x; v.w = hi.y;
    *(uint4*)(Wt + (size_t)(n0 + nr) * KP + K_DIM + r8 * 8) = v;
  }
}

// ---------------------------------------------------------------- main GEMM (256^2, BK=32, 2 blocks/CU)
__global__ __launch_bounds__(512, 4) void gemm_kernel(
    const unsigned short* __restrict__ Xe, const unsigned short* __restrict__ Wt,
    float* __restrict__ out) {
  __shared__ unsigned short lds[2][2][256 * 32];  // [buf][op A/B][256 rows x 32 k], 64 KiB
  const int tid = threadIdx.x;
  const int w = tid >> 6, lane = tid & 63;
  // T1: bijective XCD swizzle, 1376 = 8 * 172
  const int orig = blockIdx.x;
  const int wg = (orig & 7) * 172 + (orig >> 3);
  const int bm = wg & 31;   // 32 M-tiles
  const int bn = wg >> 5;   // 43 N-tiles
  const int wr = w >> 2, wc = w & 3;

  // staging: one gload covers 128 rows (8 waves x 16): lane l -> row
  // w*16 + (l>>2), phys chunk l&3. sigma(row)=row&3 -> source logical chunk
  // = (l&3) ^ ((l>>2)&3)  (pre-swizzled source, rule #21).
  const int rb = w * 16 + (lane >> 2);
  const int sc = ((lane & 3) ^ ((lane >> 2) & 3)) * 8;
  const unsigned short* gA = Xe + (size_t)(bm * 256 + rb) * KP + sc;
  const unsigned short* gB = Wt + (size_t)(bn * 256 + rb) * KP + sc;

  // fragment reads: row = base(mult 32) + (l&31) -> row&3 = l&3;
  // logical chunk = 2ks + (l>>5) -> phys = logical ^ (l&3). Even 8-lane
  // spread over all 32 banks (floor-only, no excess conflict).
  const int row32 = (lane & 31) * 32;
  int cxk[2];
#pragma unroll
  for (int ks = 0; ks < 2; ++ks)
    cxk[ks] = ((ks * 2 + (lane >> 5)) ^ (lane & 3)) * 8;

  f32x16 acc[4][2];
#pragma unroll
  for (int i = 0; i < 4; ++i)
#pragma unroll
    for (int j = 0; j < 2; ++j) acc[i][j] = (f32x16)0.f;

  bf16x8 a[4][2], b[2][2];

  // one gload_lds: rows [half*128, +128) of op region
  auto stage1 = [&](const unsigned short* g, int buf, int op, int half, int kt) {
    const unsigned short* s = g + (size_t)(half * 128) * KP + kt * 32;
    unsigned short* d = &lds[buf][op][half * 4096 + w * 512];
    GLOAD_LDS16(s, d);
  };

#define STAGE(BUF, KT)                                                         \
  do {                                                                         \
    stage1(gA, BUF, 0, 0, KT); stage1(gA, BUF, 0, 1, KT);                      \
    stage1(gB, BUF, 1, 0, KT); stage1(gB, BUF, 1, 1, KT);                      \
  } while (0)

#define LDALL(BUF)                                                             \
  do {                                                                         \
    const unsigned short* RA = &lds[BUF][0][0];                                \
    const unsigned short* RB = &lds[BUF][1][0];                                \
    _Pragma("unroll") for (int m = 0; m < 4; ++m)                              \
    _Pragma("unroll") for (int ks = 0; ks < 2; ++ks)                           \
      a[m][ks] =                                                               \
          *(const bf16x8*)(RA + wr * 4096 + m * 1024 + row32 + cxk[ks]);       \
    _Pragma("unroll") for (int n = 0; n < 2; ++n)                              \
    _Pragma("unroll") for (int ks = 0; ks < 2; ++ks)                           \
      b[n][ks] =                                                               \
          *(const bf16x8*)(RB + wc * 2048 + n * 1024 + row32 + cxk[ks]);       \
  } while (0)

#define MFMALL()                                                               \
  do {                                                                         \
    _Pragma("unroll") for (int ks = 0; ks < 2; ++ks)                           \
    _Pragma("unroll") for (int m = 0; m < 4; ++m)                              \
    _Pragma("unroll") for (int n = 0; n < 2; ++n)                              \
      acc[m][n] = __builtin_amdgcn_mfma_f32_32x32x16_bf16(                     \
          a[m][ks], b[n][ks], acc[m][n], 0, 0, 0);                             \
  } while (0)

// One K-tile: stage t+1 into buf^1, read t from buf, lgkm0, MFMA, drain
// stages, ONE barrier. Sibling block on the CU fills every stall.
#define TILE(KT, BUF, S1)                                                      \
  do {                                                                         \
    if (S1) STAGE((BUF) ^ 1, (KT) + 1);                                        \
    LDALL(BUF);                                                                \
    asm volatile("s_waitcnt lgkmcnt(0)" ::: "memory");                         \
    SB0();                                                                     \
    __builtin_amdgcn_s_setprio(1);                                             \
    MFMALL();                                                                  \
    __builtin_amdgcn_s_setprio(0);                                             \
    SB0();                                                                     \
    if (S1) { asm volatile("s_waitcnt vmcnt(0)" ::: "memory"); }               \
    SB0(); BAR(); SB0();                                                       \
  } while (0)

  // prologue: tile 0 into buf0
  STAGE(0, 0);
  asm volatile("s_waitcnt vmcnt(0)" ::: "memory");
  SB0(); BAR(); SB0();

#pragma unroll 1
  for (int kt = 0; kt < 128; kt += 2) {
    TILE(kt, 0, true);
    TILE(kt + 1, 1, true);
  }
  TILE(128, 0, true);   // stages tile 129 into buf1
  TILE(129, 1, false);

  // epilogue: 32x32 C/D layout: col = lane&31, row = (reg&3)+8*(reg>>2)+4*(lane>>5)
  const int orow = bm * 256 + wr * 128 + ((lane >> 5) << 2);
  const int ocol = bn * 256 + wc * 64 + (lane & 31);
#pragma unroll
  for (int mf = 0; mf < 4; ++mf)
#pragma unroll
    for (int nf = 0; nf < 2; ++nf)
#pragma unroll
      for (int reg = 0; reg < 16; ++reg)
        out[(size_t)(orow + mf * 32 + (reg & 3) + ((reg >> 2) << 3)) * N_DIM +
            ocol + nf * 32] = acc[mf][nf][reg];
}

// ---------------------------------------------------------------- launch
extern "C" void kernel_launch(void* const* d_in, const int* in_sizes, int n_in,
                              void* d_out, int out_size, void* d_ws, size_t ws_size,
                              hipStream_t stream) {
  const float* x = (const float*)d_in[0];
  const float* scales = (const float*)d_in[1];
  const float* lora_a = (const float*)d_in[2];
  const float* lora_b = (const float*)d_in[3];
  const int* qweight = (const int*)d_in[4];
  const int* qzeros = (const int*)d_in[5];
  float* out = (float*)d_out;

  unsigned short* Xe = (unsigned short*)d_ws;
  unsigned short* Wt = Xe + (size_t)M_DIM * KP;

  prep_x_kernel<<<M_DIM / 16, 256, 0, stream>>>(x, lora_a, Xe);
  dequant_kernel<<<dim3(N_DIM / 256, K_DIM / 64), 256, 0, stream>>>(qweight, qzeros,
                                                                    scales, Wt);
  lorab_t_kernel<<<N_DIM / 64, 256, 0, stream>>>(lora_b, Wt);
  gemm_kernel<<<dim3((N_DIM / 256) * (M_DIM / 256)), 512, 0, stream>>>(Xe, Wt, out);
}

// Round 11
// 931.706 us; speedup vs baseline: 15.9060x; 15.9060x over previous
//
#include <hip/hip_runtime.h>
#include <hip/hip_bf16.h>

// AWQ w4a16 GEMM + fused LoRA, MI355X (gfx950).
//   Xe  [8192][4160] bf16 = [ x (bf16) | t = x @ lora_a (bf16) ]
//   Wt  [11008][4160] bf16 = [ ((q - z) * s)^T | lora_b^T ]
//   out [8192][11008] f32 = Xe @ Wt^T     (K' = 4160, NT = 65 K-tiles of 64)
// GEMM r11 = r8 geometry (256x256, 8 waves 2Mx4N, BK=64, 128 KiB LDS,
// 32x32x16 MFMA, sigma(row)=(row&7)^((row>>3)&3) swizzle both sides,
// 1 block/CU, 2 waves/SIMD) with phases merged 4 -> 2 per K-tile:
//   Phase A: stage A(t+1)->buf^1 | read aX(t) | lgkm0 | MFMA mh0x{n0,n1} |
//            vmcnt(4) [drains B(t+1)] | BAR
//   Phase B: stage B(t+2)->buf   | read aY(t) | lgkm0 | MFMA mh1x{n1,n0}
//            with B(t+1) fragment pre-reads inside the cluster |
//            vmcnt(4) [drains A(t+1)] | BAR
// B-fragments reg-double-buffered (bCx/b1x vs bCy/b1y); ~126 VGPR + 128 AGPR.

typedef __bf16 bf16x8 __attribute__((ext_vector_type(8)));
typedef float f32x16 __attribute__((ext_vector_type(16)));

#define GLOAD_LDS16(gp, lp)                                                    \
  __builtin_amdgcn_global_load_lds(                                            \
      (const __attribute__((address_space(1))) void*)(gp),                     \
      (__attribute__((address_space(3))) void*)(lp), 16, 0, 0)

#define SB0() __builtin_amdgcn_sched_barrier(0)
#define BAR() __builtin_amdgcn_s_barrier()

__device__ __forceinline__ unsigned short f2b(float f) {
  unsigned int u = __builtin_bit_cast(unsigned int, f);
  unsigned int r = u + 0x7fffu + ((u >> 16) & 1u);  // RTNE
  return (unsigned short)(r >> 16);
}

constexpr int M_DIM = 8192;
constexpr int K_DIM = 4096;
constexpr int N_DIM = 11008;
constexpr int R_DIM = 64;
constexpr int KP = K_DIM + R_DIM;  // 4160
constexpr int NT = KP / 64;        // 65 K-tiles

// ---------------------------------------------------------------- prep: t = x@A, plus x->bf16
__global__ __launch_bounds__(256) void prep_x_kernel(
    const float* __restrict__ x, const float* __restrict__ A,
    unsigned short* __restrict__ Xe) {
  __shared__ float xs[16][128];
  __shared__ float as[128][64];
  const int tid = threadIdx.x;
  const int r0 = blockIdx.x * 16;
  const int c = tid & 63;
  const int rg = tid >> 6;
  float acc[4] = {0.f, 0.f, 0.f, 0.f};
  for (int kc = 0; kc < K_DIM; kc += 128) {
    __syncthreads();
#pragma unroll
    for (int i = 0; i < 2; ++i) {
      const int flat = i * 1024 + tid * 4;
      const int row = flat >> 7, col = flat & 127;
      const float4 v = *(const float4*)(x + (size_t)(r0 + row) * K_DIM + kc + col);
      *(float4*)&xs[row][col] = v;
      unsigned short h[4] = {f2b(v.x), f2b(v.y), f2b(v.z), f2b(v.w)};
      *(uint2*)(Xe + (size_t)(r0 + row) * KP + kc + col) = *(const uint2*)h;
    }
#pragma unroll
    for (int j = 0; j < 8; ++j)
      ((float4*)as)[j * 256 + tid] =
          ((const float4*)(A + (size_t)kc * R_DIM))[j * 256 + tid];
    __syncthreads();
    for (int kk = 0; kk < 128; kk += 4) {
      float4 xv[4];
#pragma unroll
      for (int i = 0; i < 4; ++i) xv[i] = *(const float4*)&xs[rg * 4 + i][kk];
#pragma unroll
      for (int q = 0; q < 4; ++q) {
        const float b = as[kk + q][c];
        acc[0] += ((const float*)&xv[0])[q] * b;
        acc[1] += ((const float*)&xv[1])[q] * b;
        acc[2] += ((const float*)&xv[2])[q] * b;
        acc[3] += ((const float*)&xv[3])[q] * b;
      }
    }
  }
#pragma unroll
  for (int i = 0; i < 4; ++i)
    Xe[(size_t)(r0 + rg * 4 + i) * KP + K_DIM + c] = f2b(acc[i]);
}

// ---------------------------------------------------------------- prep: dequant + transpose
__global__ __launch_bounds__(256) void dequant_kernel(
    const int* __restrict__ qw, const int* __restrict__ qz,
    const float* __restrict__ sc, unsigned short* __restrict__ Wt) {
  __shared__ unsigned short w_lds[64][257];
  const int tid = threadIdx.x;
  const int n0 = blockIdx.x * 256, k0 = blockIdx.y * 64;
  const int g = k0 >> 7;  // 64-k tile never crosses a 128-k group
  const int nl = (tid & 63) * 4;
  const int kb = tid >> 6;
  const int4 zq = *(const int4*)(qz + (size_t)g * N_DIM + n0 + nl);
  const float4 sv = *(const float4*)(sc + (size_t)g * N_DIM + n0 + nl);
#pragma unroll
  for (int i = 0; i < 16; ++i) {
    const int kl = i * 4 + kb;
    const int4 q = *(const int4*)(qw + (size_t)(k0 + kl) * N_DIM + n0 + nl);
    w_lds[kl][nl + 0] = f2b((float)(q.x - zq.x) * sv.x);
    w_lds[kl][nl + 1] = f2b((float)(q.y - zq.y) * sv.y);
    w_lds[kl][nl + 2] = f2b((float)(q.z - zq.z) * sv.z);
    w_lds[kl][nl + 3] = f2b((float)(q.w - zq.w) * sv.w);
  }
  __syncthreads();
  const int c = tid & 7;         // k-chunk (8 k = 16B)
  const int ns = (tid >> 3) & 7; // n-sub within wave
  const int w = tid >> 6;
#pragma unroll
  for (int v = 0; v < 8; ++v) {
    const int n = w * 64 + v * 8 + ns;
    unsigned short tmp[8];
#pragma unroll
    for (int i = 0; i < 8; ++i) tmp[i] = w_lds[c * 8 + i][n];
    *(uint4*)(Wt + (size_t)(n0 + n) * KP + k0 + c * 8) = *(const uint4*)tmp;
  }
}

// ---------------------------------------------------------------- prep: lora_b^T
__global__ __launch_bounds__(256) void lorab_t_kernel(
    const float* __restrict__ B, unsigned short* __restrict__ Wt) {
  __shared__ unsigned short b_lds[64][68];
  const int tid = threadIdx.x;
  const int n0 = blockIdx.x * 64;
  const int nl = tid & 63;
  const int rl0 = tid >> 6;
#pragma unroll
  for (int i = 0; i < 16; ++i) {
    const int rl = i * 4 + rl0;
    b_lds[nl][rl] = f2b(B[(size_t)rl * N_DIM + n0 + nl]);
  }
  __syncthreads();
#pragma unroll
  for (int p = 0; p < 2; ++p) {
    const int chunk = p * 256 + tid;
    const int nr = chunk >> 3, r8 = chunk & 7;
    const unsigned short* rp = &b_lds[nr][r8 * 8];
    const uint2 lo = *(const uint2*)rp;
    const uint2 hi = *(const uint2*)(rp + 4);
    uint4 v;
    v.x = lo.x; v.y = lo.y; v.z = hi.x; v.w = hi.y;
    *(uint4*)(Wt + (size_t)(n0 + nr) * KP + K_DIM + r8 * 8) = v;
  }
}

// ---------------------------------------------------------------- main GEMM
__global__ __launch_bounds__(512, 2) void gemm_kernel(
    const unsigned short* __restrict__ Xe, const unsigned short* __restrict__ Wt,
    float* __restrict__ out) {
  __shared__ unsigned short lds[2][2][2][128 * 64];
  const int tid = threadIdx.x;
  const int w = tid >> 6, lane = tid & 63;
  // T1: bijective XCD swizzle, 1376 = 8 * 172
  const int orig = blockIdx.x;
  const int wg = (orig & 7) * 172 + (orig >> 3);
  const int bm = wg & 31;   // 32 M-tiles
  const int bn = wg >> 5;   // 43 N-tiles
  const int wr = w >> 2, wc = w & 3;

  // staging: lane l writes phys chunk (l&7) of stripe-row w*8+(l>>3); source
  // logical chunk = (l&7) ^ sigma(row), sigma(row) = (row&7)^((row>>3)&3)
  const int rb = w * 8 + (lane >> 3);
  const int sc = ((lane & 7) ^ (lane >> 3) ^ (w & 3)) * 8;
  const unsigned short* gA = Xe + (size_t)(bm * 256 + rb) * KP + sc;
  const unsigned short* gB = Wt + (size_t)(bn * 256 + rb) * KP + sc;

  // fragment reads: row r = l&31 (+32 multiples), phys chunk =
  // logical ^ (l&7) ^ ((l>>3)&3) -- bank-spread (r7-verified, 0 conflicts)
  const int rowA32 = (lane & 31) * 64;
  const int rowB32 = ((wc & 1) * 64 + (lane & 31)) * 64;
  int cxk[4];
#pragma unroll
  for (int ks = 0; ks < 4; ++ks)
    cxk[ks] = ((ks * 2 + (lane >> 5)) ^ (lane & 7) ^ ((lane >> 3) & 3)) * 8;

  f32x16 acc[4][2];
#pragma unroll
  for (int i = 0; i < 4; ++i)
#pragma unroll
    for (int j = 0; j < 2; ++j) acc[i][j] = (f32x16)0.f;

  bf16x8 a[2][4], bCx[4], b1x[4], bCy[4], b1y[4];

  // one gload_lds: rows [rq*64, rq*64+64) of region [op][half]
  auto stage1 = [&](const unsigned short* g, int buf, int op, int half, int rq,
                    int kt) {
    const unsigned short* s = g + (size_t)(half * 128 + rq * 64) * KP + kt * 64;
    unsigned short* d = &lds[buf][op][half][rq * 4096 + w * 512];
    GLOAD_LDS16(s, d);
  };

#define LDA(BUF, mh)                                                           \
  do {                                                                         \
    const unsigned short* R = &lds[BUF][0][wr][0];                             \
    _Pragma("unroll") for (int i = 0; i < 2; ++i)                              \
    _Pragma("unroll") for (int ks = 0; ks < 4; ++ks)                           \
      a[i][ks] =                                                               \
          *(const bf16x8*)(R + ((mh)*2 + i) * 2048 + rowA32 + cxk[ks]);        \
  } while (0)

#define LDB(BUF, dst, nh)                                                      \
  do {                                                                         \
    const unsigned short* R = &lds[BUF][1][wc >> 1][0];                        \
    _Pragma("unroll") for (int ks = 0; ks < 4; ++ks)                           \
      dst[ks] = *(const bf16x8*)(R + (nh)*2048 + rowB32 + cxk[ks]);            \
  } while (0)

#define MFMAQ(mh, bb, nh)                                                      \
  do {                                                                         \
    _Pragma("unroll") for (int ks = 0; ks < 4; ++ks)                           \
    _Pragma("unroll") for (int i = 0; i < 2; ++i)                              \
      acc[(mh)*2 + i][nh] = __builtin_amdgcn_mfma_f32_32x32x16_bf16(           \
          a[i][ks], bb[ks], acc[(mh)*2 + i][nh], 0, 0, 0);                     \
  } while (0)

#define LGKM0() do { asm volatile("s_waitcnt lgkmcnt(0)" ::: "memory"); SB0(); } while (0)
#define PRIO_ON()  __builtin_amdgcn_s_setprio(1)
#define PRIO_OFF() __builtin_amdgcn_s_setprio(0)
#define VM4() asm volatile("s_waitcnt vmcnt(4)" ::: "memory")
#define VM0() asm volatile("s_waitcnt vmcnt(0)" ::: "memory")
#define VNOP() ((void)0)

// One K-tile, TWO phases. CC/C1 = this tile's B fragments (n0/n1, pre-read
// last tile); NC/N1 receive next tile's at phase B (PRE). Stages: A(kt+1)
// ->BUF^1 at phase A, B(kt+2)->BUF at phase B (both regions of BUF B dead:
// fragments were pre-read). VA=vmcnt(4) end-A drains B(kt+1) [outstanding =
// B(kt+1)4 + A(kt+1)4]; VB=vmcnt(4) end-B drains A(kt+1) [outstanding =
// A(kt+1)4 + B(kt+2)4].
#define TILE2(KT, BUF, CC, C1, NC, N1, S1, S2, VA, VB, PRE)                    \
  do {                                                                         \
    const int kt_ = (KT);                                                      \
    /* phase A */                                                              \
    if (S1) { stage1(gA, (BUF) ^ 1, 0, 0, 0, kt_ + 1);                         \
              stage1(gA, (BUF) ^ 1, 0, 1, 0, kt_ + 1);                         \
              stage1(gA, (BUF) ^ 1, 0, 0, 1, kt_ + 1);                         \
              stage1(gA, (BUF) ^ 1, 0, 1, 1, kt_ + 1); }                       \
    LDA(BUF, 0);                                                               \
    LGKM0();                                                                   \
    PRIO_ON(); MFMAQ(0, CC, 0); MFMAQ(0, C1, 1); PRIO_OFF();                   \
    SB0(); VA(); SB0(); BAR(); SB0();                                          \
    /* phase B */                                                              \
    if (S2) { stage1(gB, (BUF), 1, 0, 0, kt_ + 2);                             \
              stage1(gB, (BUF), 1, 1, 0, kt_ + 2);                             \
              stage1(gB, (BUF), 1, 0, 1, kt_ + 2);                             \
              stage1(gB, (BUF), 1, 1, 1, kt_ + 2); }                           \
    LDA(BUF, 1);                                                               \
    LGKM0();                                                                   \
    PRIO_ON(); MFMAQ(1, C1, 1);                                                \
    if (PRE) { LDB((BUF) ^ 1, NC, 0); }                                        \
    MFMAQ(1, CC, 0);                                                           \
    if (PRE) { LDB((BUF) ^ 1, N1, 1); }                                        \
    PRIO_OFF();                                                                \
    SB0(); VB(); SB0(); BAR(); SB0();                                          \
  } while (0)

  // prologue: A(0) 4, B(0) 4, B(1) 4 gloads; vmcnt(4) -> tile0 landed,
  // B(1) in flight; then pre-read tile0's B fragments.
  stage1(gA, 0, 0, 0, 0, 0); stage1(gA, 0, 0, 1, 0, 0);
  stage1(gA, 0, 0, 0, 1, 0); stage1(gA, 0, 0, 1, 1, 0);
  stage1(gB, 0, 1, 0, 0, 0); stage1(gB, 0, 1, 1, 0, 0);
  stage1(gB, 0, 1, 0, 1, 0); stage1(gB, 0, 1, 1, 1, 0);
  stage1(gB, 1, 1, 0, 0, 1); stage1(gB, 1, 1, 1, 0, 1);
  stage1(gB, 1, 1, 0, 1, 1); stage1(gB, 1, 1, 1, 1, 1);
  SB0(); VM4(); SB0(); BAR(); SB0();
  LDB(0, bCx, 0);   // B(0) n0  (awaited by tile0 phase A's LGKM0)
  LDB(0, b1x, 1);   // B(0) n1

#pragma unroll 1
  for (int kt = 0; kt < 62; kt += 2) {
    TILE2(kt,     0, bCx, b1x, bCy, b1y, true, true, VM4, VM4, true);
    TILE2(kt + 1, 1, bCy, b1y, bCx, b1x, true, true, VM4, VM4, true);
  }
  TILE2(62, 0, bCx, b1x, bCy, b1y, true,  true,  VM4,  VM4,  true);
  TILE2(63, 1, bCy, b1y, bCx, b1x, true,  false, VM4,  VM0,  true);
  TILE2(64, 0, bCx, b1x, bCy, b1y, false, false, VNOP, VNOP, false);

  // epilogue: 32x32 C/D layout: col = lane&31, row = (reg&3)+8*(reg>>2)+4*(lane>>5)
  const int orow = bm * 256 + wr * 128 + ((lane >> 5) << 2);
  const int ocol = bn * 256 + wc * 64 + (lane & 31);
#pragma unroll
  for (int mf = 0; mf < 4; ++mf)
#pragma unroll
    for (int nf = 0; nf < 2; ++nf)
#pragma unroll
      for (int reg = 0; reg < 16; ++reg)
        out[(size_t)(orow + mf * 32 + (reg & 3) + ((reg >> 2) << 3)) * N_DIM +
            ocol + nf * 32] = acc[mf][nf][reg];
}

// ---------------------------------------------------------------- launch
extern "C" void kernel_launch(void* const* d_in, const int* in_sizes, int n_in,
                              void* d_out, int out_size, void* d_ws, size_t ws_size,
                              hipStream_t stream) {
  const float* x = (const float*)d_in[0];
  const float* scales = (const float*)d_in[1];
  const float* lora_a = (const float*)d_in[2];
  const float* lora_b = (const float*)d_in[3];
  const int* qweight = (const int*)d_in[4];
  const int* qzeros = (const int*)d_in[5];
  float* out = (float*)d_out;

  unsigned short* Xe = (unsigned short*)d_ws;
  unsigned short* Wt = Xe + (size_t)M_DIM * KP;

  prep_x_kernel<<<M_DIM / 16, 256, 0, stream>>>(x, lora_a, Xe);
  dequant_kernel<<<dim3(N_DIM / 256, K_DIM / 64), 256, 0, stream>>>(qweight, qzeros,
                                                                    scales, Wt);
  lorab_t_kernel<<<N_DIM / 64, 256, 0, stream>>>(lora_b, Wt);
  gemm_kernel<<<dim3((N_DIM / 256) * (M_DIM / 256)), 512, 0, stream>>>(Xe, Wt, out);
}

// Round 12
// 893.863 us; speedup vs baseline: 16.5794x; 1.0423x over previous
//
#include <hip/hip_runtime.h>
#include <hip/hip_bf16.h>

// AWQ w4a16 GEMM + fused LoRA, MI355X (gfx950).
//   Xe  [8192][4160] bf16 = [ x (bf16) | t = x @ lora_a (bf16) ]
//   Wt  [11008][4160] bf16 = [ ((q - z) * s)^T | lora_b^T ]
//   out [8192][11008] f32 = Xe @ Wt^T     (K' = 4160, NT = 65 K-tiles of 64)
// GEMM r12 = r8 (256x256, 8 waves 2Mx4N, BK=64, 128 KiB LDS, 32x32x16 MFMA,
// sigma(row)=(row&7)^((row>>3)&3) swizzle both sides, 4 intervals/K-tile,
// reads pipelined one interval ahead, vmcnt(4)/(2) counted)
// + T19 sched_group_barrier pinning: per interval the scheduler must emit
// {MFMA 1, DS_READ 1, VMEM 1} interleaved (compiler was hoisting all
// ds_reads ahead of the MFMA cluster -> LDS burst + MFMA burst serialized;
// measured phase = 576 LDS + 512 MFMA = 1088 cyc, 4200/tile ~= measured).

typedef __bf16 bf16x8 __attribute__((ext_vector_type(8)));
typedef float f32x16 __attribute__((ext_vector_type(16)));

#define GLOAD_LDS16(gp, lp)                                                    \
  __builtin_amdgcn_global_load_lds(                                            \
      (const __attribute__((address_space(1))) void*)(gp),                     \
      (__attribute__((address_space(3))) void*)(lp), 16, 0, 0)

#define SB0() __builtin_amdgcn_sched_barrier(0)
#define BAR() __builtin_amdgcn_s_barrier()

// T19: interleave R ds_reads and G vmem ops among the 8 MFMAs of a cluster.
// Masks (LLVM SchedGroupMask): MFMA=0x8, DS_READ=0x100, VMEM=0x10.
#define ILV(R, G)                                                              \
  do {                                                                         \
    _Pragma("unroll") for (int ii = 0; ii < 8; ++ii) {                         \
      __builtin_amdgcn_sched_group_barrier(0x8, 1, 0);                         \
      if (ii < (R)) __builtin_amdgcn_sched_group_barrier(0x100, 1, 0);         \
      if (ii < (G)) __builtin_amdgcn_sched_group_barrier(0x10, 1, 0);          \
    }                                                                          \
  } while (0)

__device__ __forceinline__ unsigned short f2b(float f) {
  unsigned int u = __builtin_bit_cast(unsigned int, f);
  unsigned int r = u + 0x7fffu + ((u >> 16) & 1u);  // RTNE
  return (unsigned short)(r >> 16);
}

constexpr int M_DIM = 8192;
constexpr int K_DIM = 4096;
constexpr int N_DIM = 11008;
constexpr int R_DIM = 64;
constexpr int KP = K_DIM + R_DIM;  // 4160
constexpr int NT = KP / 64;        // 65 K-tiles

// ---------------------------------------------------------------- prep: t = x@A, plus x->bf16
__global__ __launch_bounds__(256) void prep_x_kernel(
    const float* __restrict__ x, const float* __restrict__ A,
    unsigned short* __restrict__ Xe) {
  __shared__ float xs[16][128];
  __shared__ float as[128][64];
  const int tid = threadIdx.x;
  const int r0 = blockIdx.x * 16;
  const int c = tid & 63;
  const int rg = tid >> 6;
  float acc[4] = {0.f, 0.f, 0.f, 0.f};
  for (int kc = 0; kc < K_DIM; kc += 128) {
    __syncthreads();
#pragma unroll
    for (int i = 0; i < 2; ++i) {
      const int flat = i * 1024 + tid * 4;
      const int row = flat >> 7, col = flat & 127;
      const float4 v = *(const float4*)(x + (size_t)(r0 + row) * K_DIM + kc + col);
      *(float4*)&xs[row][col] = v;
      unsigned short h[4] = {f2b(v.x), f2b(v.y), f2b(v.z), f2b(v.w)};
      *(uint2*)(Xe + (size_t)(r0 + row) * KP + kc + col) = *(const uint2*)h;
    }
#pragma unroll
    for (int j = 0; j < 8; ++j)
      ((float4*)as)[j * 256 + tid] =
          ((const float4*)(A + (size_t)kc * R_DIM))[j * 256 + tid];
    __syncthreads();
    for (int kk = 0; kk < 128; kk += 4) {
      float4 xv[4];
#pragma unroll
      for (int i = 0; i < 4; ++i) xv[i] = *(const float4*)&xs[rg * 4 + i][kk];
#pragma unroll
      for (int q = 0; q < 4; ++q) {
        const float b = as[kk + q][c];
        acc[0] += ((const float*)&xv[0])[q] * b;
        acc[1] += ((const float*)&xv[1])[q] * b;
        acc[2] += ((const float*)&xv[2])[q] * b;
        acc[3] += ((const float*)&xv[3])[q] * b;
      }
    }
  }
#pragma unroll
  for (int i = 0; i < 4; ++i)
    Xe[(size_t)(r0 + rg * 4 + i) * KP + K_DIM + c] = f2b(acc[i]);
}

// ---------------------------------------------------------------- prep: dequant + transpose
__global__ __launch_bounds__(256) void dequant_kernel(
    const int* __restrict__ qw, const int* __restrict__ qz,
    const float* __restrict__ sc, unsigned short* __restrict__ Wt) {
  __shared__ unsigned short w_lds[64][257];
  const int tid = threadIdx.x;
  const int n0 = blockIdx.x * 256, k0 = blockIdx.y * 64;
  const int g = k0 >> 7;  // 64-k tile never crosses a 128-k group
  const int nl = (tid & 63) * 4;
  const int kb = tid >> 6;
  const int4 zq = *(const int4*)(qz + (size_t)g * N_DIM + n0 + nl);
  const float4 sv = *(const float4*)(sc + (size_t)g * N_DIM + n0 + nl);
#pragma unroll
  for (int i = 0; i < 16; ++i) {
    const int kl = i * 4 + kb;
    const int4 q = *(const int4*)(qw + (size_t)(k0 + kl) * N_DIM + n0 + nl);
    w_lds[kl][nl + 0] = f2b((float)(q.x - zq.x) * sv.x);
    w_lds[kl][nl + 1] = f2b((float)(q.y - zq.y) * sv.y);
    w_lds[kl][nl + 2] = f2b((float)(q.z - zq.z) * sv.z);
    w_lds[kl][nl + 3] = f2b((float)(q.w - zq.w) * sv.w);
  }
  __syncthreads();
  const int c = tid & 7;         // k-chunk (8 k = 16B)
  const int ns = (tid >> 3) & 7; // n-sub within wave
  const int w = tid >> 6;
#pragma unroll
  for (int v = 0; v < 8; ++v) {
    const int n = w * 64 + v * 8 + ns;
    unsigned short tmp[8];
#pragma unroll
    for (int i = 0; i < 8; ++i) tmp[i] = w_lds[c * 8 + i][n];
    *(uint4*)(Wt + (size_t)(n0 + n) * KP + k0 + c * 8) = *(const uint4*)tmp;
  }
}

// ---------------------------------------------------------------- prep: lora_b^T
__global__ __launch_bounds__(256) void lorab_t_kernel(
    const float* __restrict__ B, unsigned short* __restrict__ Wt) {
  __shared__ unsigned short b_lds[64][68];
  const int tid = threadIdx.x;
  const int n0 = blockIdx.x * 64;
  const int nl = tid & 63;
  const int rl0 = tid >> 6;
#pragma unroll
  for (int i = 0; i < 16; ++i) {
    const int rl = i * 4 + rl0;
    b_lds[nl][rl] = f2b(B[(size_t)rl * N_DIM + n0 + nl]);
  }
  __syncthreads();
#pragma unroll
  for (int p = 0; p < 2; ++p) {
    const int chunk = p * 256 + tid;
    const int nr = chunk >> 3, r8 = chunk & 7;
    const unsigned short* rp = &b_lds[nr][r8 * 8];
    const uint2 lo = *(const uint2*)rp;
    const uint2 hi = *(const uint2*)(rp + 4);
    uint4 v;
    v.x = lo.x; v.y = lo.y; v.z = hi.x; v.w = hi.y;
    *(uint4*)(Wt + (size_t)(n0 + nr) * KP + K_DIM + r8 * 8) = v;
  }
}

// ---------------------------------------------------------------- main GEMM
__global__ __launch_bounds__(512, 2) void gemm_kernel(
    const unsigned short* __restrict__ Xe, const unsigned short* __restrict__ Wt,
    float* __restrict__ out) {
  __shared__ unsigned short lds[2][2][2][128 * 64];
  const int tid = threadIdx.x;
  const int w = tid >> 6, lane = tid & 63;
  // T1: bijective XCD swizzle, 1376 = 8 * 172
  const int orig = blockIdx.x;
  const int wg = (orig & 7) * 172 + (orig >> 3);
  const int bm = wg & 31;   // 32 M-tiles
  const int bn = wg >> 5;   // 43 N-tiles
  const int wr = w >> 2, wc = w & 3;

  // staging: lane l writes phys chunk (l&7) of stripe-row w*8+(l>>3); source
  // logical chunk = (l&7) ^ sigma(row), sigma(row) = (row&7)^((row>>3)&3)
  const int rb = w * 8 + (lane >> 3);
  const int sc = ((lane & 7) ^ (lane >> 3) ^ (w & 3)) * 8;
  const unsigned short* gA = Xe + (size_t)(bm * 256 + rb) * KP + sc;
  const unsigned short* gB = Wt + (size_t)(bn * 256 + rb) * KP + sc;

  // fragment reads: row r = l&31 (+32 multiples), phys chunk =
  // logical ^ (l&7) ^ ((l>>3)&3) -- bank-spread (r7-verified, 0 conflicts)
  const int rowA32 = (lane & 31) * 64;
  const int rowB32 = ((wc & 1) * 64 + (lane & 31)) * 64;
  int cxk[4];
#pragma unroll
  for (int ks = 0; ks < 4; ++ks)
    cxk[ks] = ((ks * 2 + (lane >> 5)) ^ (lane & 7) ^ ((lane >> 3) & 3)) * 8;

  f32x16 acc[4][2];
#pragma unroll
  for (int i = 0; i < 4; ++i)
#pragma unroll
    for (int j = 0; j < 2; ++j) acc[i][j] = (f32x16)0.f;

  bf16x8 a[2][4], b0x[4], b0y[4], b1[4];

  // one gload_lds: rows [rq*64, rq*64+64) of region [op][half]
  auto stage1 = [&](const unsigned short* g, int buf, int op, int half, int rq,
                    int kt) {
    const unsigned short* s = g + (size_t)(half * 128 + rq * 64) * KP + kt * 64;
    unsigned short* d = &lds[buf][op][half][rq * 4096 + w * 512];
    GLOAD_LDS16(s, d);
  };

#define LDA(BUF, mh)                                                           \
  do {                                                                         \
    const unsigned short* R = &lds[BUF][0][wr][0];                             \
    _Pragma("unroll") for (int i = 0; i < 2; ++i)                              \
    _Pragma("unroll") for (int ks = 0; ks < 4; ++ks)                           \
      a[i][ks] =                                                               \
          *(const bf16x8*)(R + ((mh)*2 + i) * 2048 + rowA32 + cxk[ks]);        \
  } while (0)

#define LDB(BUF, dst, nh)                                                      \
  do {                                                                         \
    const unsigned short* R = &lds[BUF][1][wc >> 1][0];                        \
    _Pragma("unroll") for (int ks = 0; ks < 4; ++ks)                           \
      dst[ks] = *(const bf16x8*)(R + (nh)*2048 + rowB32 + cxk[ks]);            \
  } while (0)

#define MFMAQ(mh, bb, nh)                                                      \
  do {                                                                         \
    _Pragma("unroll") for (int ks = 0; ks < 4; ++ks)                           \
    _Pragma("unroll") for (int i = 0; i < 2; ++i)                              \
      acc[(mh)*2 + i][nh] = __builtin_amdgcn_mfma_f32_32x32x16_bf16(           \
          a[i][ks], bb[ks], acc[(mh)*2 + i][nh], 0, 0, 0);                     \
  } while (0)

#define LGKM0() do { asm volatile("s_waitcnt lgkmcnt(0)" ::: "memory"); SB0(); } while (0)
#define PRIO_ON()  __builtin_amdgcn_s_setprio(1)
#define PRIO_OFF() __builtin_amdgcn_s_setprio(0)
#define VM4() asm volatile("s_waitcnt vmcnt(4)" ::: "memory")
#define VM2() asm volatile("s_waitcnt vmcnt(2)" ::: "memory")
#define VM0() asm volatile("s_waitcnt vmcnt(0)" ::: "memory")
#define VNOP() ((void)0)

// One K-tile, 4 intervals, 1 barrier each. MFMA consumes fragments read last
// interval; this interval's reads (for next) and stages overlap the MFMAs,
// interleave enforced by ILV (T19). VMA end-I2 drains B(kt+1) for I3's read;
// VMB end-I3 drains A(kt+1) for I4's read.
#define TILE(KT, BUF, CURB, NXTB, S1, S2, VMA, VMB, LAST)                      \
  do {                                                                         \
    const int kt_ = (KT);                                                      \
    /* I1: 8 MFMA | 4 ds_read | 2 vmem */                                      \
    LGKM0();                                                                   \
    PRIO_ON(); MFMAQ(0, CURB, 0);                                              \
    LDB(BUF, b1, 1);                                                           \
    PRIO_OFF();                                                                \
    if (S1) { stage1(gA, (BUF) ^ 1, 0, 0, 0, kt_ + 1);                         \
              stage1(gA, (BUF) ^ 1, 0, 1, 0, kt_ + 1); }                       \
    ILV(4, (S1) ? 2 : 0);                                                      \
    SB0(); BAR(); SB0();                                                       \
    /* I2: 8 MFMA | 8 ds_read | 2 vmem */                                      \
    LGKM0();                                                                   \
    PRIO_ON(); MFMAQ(0, b1, 1);                                                \
    LDA(BUF, 1);                                                               \
    PRIO_OFF();                                                                \
    if (S1) { stage1(gA, (BUF) ^ 1, 0, 0, 1, kt_ + 1);                         \
              stage1(gA, (BUF) ^ 1, 0, 1, 1, kt_ + 1); }                       \
    ILV(8, (S1) ? 2 : 0);                                                      \
    SB0(); VMA(); SB0(); BAR(); SB0();                                         \
    /* I3: 8 MFMA | 4 ds_read | 2 vmem */                                      \
    LGKM0();                                                                   \
    PRIO_ON(); MFMAQ(1, b1, 1);                                                \
    if (!(LAST)) { LDB((BUF) ^ 1, NXTB, 0); }                                  \
    PRIO_OFF();                                                                \
    if (S2) { stage1(gB, (BUF), 1, 0, 0, kt_ + 2);                             \
              stage1(gB, (BUF), 1, 1, 0, kt_ + 2); }                           \
    ILV((LAST) ? 0 : 4, (S2) ? 2 : 0);                                         \
    SB0(); VMB(); SB0(); BAR(); SB0();                                         \
    /* I4: 8 MFMA | 8 ds_read | 2 vmem */                                      \
    LGKM0();                                                                   \
    PRIO_ON(); MFMAQ(1, CURB, 0);                                              \
    if (!(LAST)) { LDA((BUF) ^ 1, 0); }                                        \
    PRIO_OFF();                                                                \
    if (S2) { stage1(gB, (BUF), 1, 0, 1, kt_ + 2);                             \
              stage1(gB, (BUF), 1, 1, 1, kt_ + 2); }                           \
    ILV((LAST) ? 0 : 8, (S2) ? 2 : 0);                                         \
    SB0(); BAR(); SB0();                                                       \
  } while (0)

  // prologue: stage A(0) q0,q1 (4), B(0) (4), B(1) (4); vmcnt(4) -> tile0
  // landed, B(1) in flight; then initial fragment reads.
  stage1(gA, 0, 0, 0, 0, 0); stage1(gA, 0, 0, 1, 0, 0);
  stage1(gA, 0, 0, 0, 1, 0); stage1(gA, 0, 0, 1, 1, 0);
  stage1(gB, 0, 1, 0, 0, 0); stage1(gB, 0, 1, 1, 0, 0);
  stage1(gB, 0, 1, 0, 1, 0); stage1(gB, 0, 1, 1, 1, 0);
  stage1(gB, 1, 1, 0, 0, 1); stage1(gB, 1, 1, 1, 0, 1);
  stage1(gB, 1, 1, 0, 1, 1); stage1(gB, 1, 1, 1, 1, 1);
  SB0(); VM4(); SB0(); BAR(); SB0();
  LDA(0, 0);          // a = mh0(0)
  LDB(0, b0x, 0);     // b0x = B(0) n0   (awaited by tile0 I1's LGKM0)

#pragma unroll 1
  for (int kt = 0; kt < 62; kt += 2) {
    TILE(kt,     0, b0x, b0y, true, true, VM4, VM2, false);
    TILE(kt + 1, 1, b0y, b0x, true, true, VM4, VM2, false);
  }
  TILE(62, 0, b0x, b0y, true,  true,  VM4,  VM2,  false);
  TILE(63, 1, b0y, b0x, true,  false, VM4,  VM0,  false);
  TILE(64, 0, b0x, b0y, false, false, VNOP, VNOP, true);

  // epilogue: 32x32 C/D layout: col = lane&31, row = (reg&3)+8*(reg>>2)+4*(lane>>5)
  const int orow = bm * 256 + wr * 128 + ((lane >> 5) << 2);
  const int ocol = bn * 256 + wc * 64 + (lane & 31);
#pragma unroll
  for (int mf = 0; mf < 4; ++mf)
#pragma unroll
    for (int nf = 0; nf < 2; ++nf)
#pragma unroll
      for (int reg = 0; reg < 16; ++reg)
        out[(size_t)(orow + mf * 32 + (reg & 3) + ((reg >> 2) << 3)) * N_DIM +
            ocol + nf * 32] = acc[mf][nf][reg];
}

// ---------------------------------------------------------------- launch
extern "C" void kernel_launch(void* const* d_in, const int* in_sizes, int n_in,
                              void* d_out, int out_size, void* d_ws, size_t ws_size,
                              hipStream_t stream) {
  const float* x = (const float*)d_in[0];
  const float* scales = (const float*)d_in[1];
  const float* lora_a = (const float*)d_in[2];
  const float* lora_b = (const float*)d_in[3];
  const int* qweight = (const int*)d_in[4];
  const int* qzeros = (const int*)d_in[5];
  float* out = (float*)d_out;

  unsigned short* Xe = (unsigned short*)d_ws;
  unsigned short* Wt = Xe + (size_t)M_DIM * KP;

  prep_x_kernel<<<M_DIM / 16, 256, 0, stream>>>(x, lora_a, Xe);
  dequant_kernel<<<dim3(N_DIM / 256, K_DIM / 64), 256, 0, stream>>>(qweight, qzeros,
                                                                    scales, Wt);
  lorab_t_kernel<<<N_DIM / 64, 256, 0, stream>>>(lora_b, Wt);
  gemm_kernel<<<dim3((N_DIM / 256) * (M_DIM / 256)), 512, 0, stream>>>(Xe, Wt, out);
}

// Round 13
// 852.442 us; speedup vs baseline: 17.3851x; 1.0486x over previous
//
#include <hip/hip_runtime.h>
#include <hip/hip_bf16.h>

// AWQ w4a16 GEMM + fused LoRA, MI355X (gfx950).
//   Xe  [8192][4160] bf16 = [ x (bf16) | t = x @ lora_a (bf16) ]
//   Wt  [11008][4160] bf16 = [ ((q - z) * s)^T | lora_b^T ]
//   out [8192][11008] f32 = Xe @ Wt^T     (K' = 4160, NT = 65 K-tiles of 64)
// r13: GEMM identical to r12 (best: 671-683 us, MfmaUtil ~53%). All three
// prep kernels merged into ONE launch (blockIdx-range dispatch, shared smem
// arena) so prep_x (FMA-bound, 512 blocks) overlaps dequant (mem-bound,
// 2752 blocks) + lorab_t (172) -- was 219 us serialized, ~90 us work floor.

typedef __bf16 bf16x8 __attribute__((ext_vector_type(8)));
typedef float f32x16 __attribute__((ext_vector_type(16)));

#define GLOAD_LDS16(gp, lp)                                                    \
  __builtin_amdgcn_global_load_lds(                                            \
      (const __attribute__((address_space(1))) void*)(gp),                     \
      (__attribute__((address_space(3))) void*)(lp), 16, 0, 0)

#define SB0() __builtin_amdgcn_sched_barrier(0)
#define BAR() __builtin_amdgcn_s_barrier()

// T19: interleave R ds_reads and G vmem ops among the 8 MFMAs of a cluster.
#define ILV(R, G)                                                              \
  do {                                                                         \
    _Pragma("unroll") for (int ii = 0; ii < 8; ++ii) {                         \
      __builtin_amdgcn_sched_group_barrier(0x8, 1, 0);                         \
      if (ii < (R)) __builtin_amdgcn_sched_group_barrier(0x100, 1, 0);         \
      if (ii < (G)) __builtin_amdgcn_sched_group_barrier(0x10, 1, 0);          \
    }                                                                          \
  } while (0)

__device__ __forceinline__ unsigned short f2b(float f) {
  unsigned int u = __builtin_bit_cast(unsigned int, f);
  unsigned int r = u + 0x7fffu + ((u >> 16) & 1u);  // RTNE
  return (unsigned short)(r >> 16);
}

constexpr int M_DIM = 8192;
constexpr int K_DIM = 4096;
constexpr int N_DIM = 11008;
constexpr int R_DIM = 64;
constexpr int KP = K_DIM + R_DIM;  // 4160
constexpr int NT = KP / 64;        // 65 K-tiles

constexpr int NPX = M_DIM / 16;                 // 512 prep_x blocks
constexpr int NDQ = (N_DIM / 256) * (K_DIM / 64);  // 43*64 = 2752 dequant blocks
constexpr int NLB = N_DIM / 64;                 // 172 lorab blocks

// ---------------------------------------------------------------- merged prep
// blocks [0, NPX): prep_x (t = x@A + x->bf16). FMA-bound, longest -> first.
// blocks [NPX, NPX+NDQ): dequant+transpose.  blocks [NPX+NDQ, +NLB): lorab^T.
__global__ __launch_bounds__(256) void prep_all_kernel(
    const float* __restrict__ x, const float* __restrict__ A,
    const float* __restrict__ B, const int* __restrict__ qw,
    const int* __restrict__ qz, const float* __restrict__ sc,
    unsigned short* __restrict__ Xe, unsigned short* __restrict__ Wt) {
  __shared__ __align__(16) char smem[41088];
  const int bid = blockIdx.x;
  const int tid = threadIdx.x;

  if (bid < NPX) {
    // ---------------- prep_x: 16 rows of t = x@A, plus x->bf16 passthrough
    float (*xs)[128] = (float (*)[128])smem;              // 16x128 f32, 8 KB
    float (*as)[64] = (float (*)[64])(smem + 8192);       // 128x64 f32, 32 KB
    const int r0 = bid * 16;
    const int c = tid & 63;
    const int rg = tid >> 6;
    float acc[4] = {0.f, 0.f, 0.f, 0.f};
    for (int kc = 0; kc < K_DIM; kc += 128) {
      __syncthreads();
#pragma unroll
      for (int i = 0; i < 2; ++i) {
        const int flat = i * 1024 + tid * 4;
        const int row = flat >> 7, col = flat & 127;
        const float4 v =
            *(const float4*)(x + (size_t)(r0 + row) * K_DIM + kc + col);
        *(float4*)&xs[row][col] = v;
        unsigned short h[4] = {f2b(v.x), f2b(v.y), f2b(v.z), f2b(v.w)};
        *(uint2*)(Xe + (size_t)(r0 + row) * KP + kc + col) = *(const uint2*)h;
      }
#pragma unroll
      for (int j = 0; j < 8; ++j)
        ((float4*)as)[j * 256 + tid] =
            ((const float4*)(A + (size_t)kc * R_DIM))[j * 256 + tid];
      __syncthreads();
      for (int kk = 0; kk < 128; kk += 4) {
        float4 xv[4];
#pragma unroll
        for (int i = 0; i < 4; ++i) xv[i] = *(const float4*)&xs[rg * 4 + i][kk];
#pragma unroll
        for (int q = 0; q < 4; ++q) {
          const float b = as[kk + q][c];
          acc[0] += ((const float*)&xv[0])[q] * b;
          acc[1] += ((const float*)&xv[1])[q] * b;
          acc[2] += ((const float*)&xv[2])[q] * b;
          acc[3] += ((const float*)&xv[3])[q] * b;
        }
      }
    }
#pragma unroll
    for (int i = 0; i < 4; ++i)
      Xe[(size_t)(r0 + rg * 4 + i) * KP + K_DIM + c] = f2b(acc[i]);

  } else if (bid < NPX + NDQ) {
    // ---------------- dequant + transpose, tile 64k x 256n
    unsigned short (*w_lds)[257] = (unsigned short (*)[257])smem;  // 32.9 KB
    const int i2 = bid - NPX;
    const int n0 = (i2 % (N_DIM / 256)) * 256;
    const int k0 = (i2 / (N_DIM / 256)) * 64;
    const int g = k0 >> 7;  // 64-k tile never crosses a 128-k group
    const int nl = (tid & 63) * 4;
    const int kb = tid >> 6;
    const int4 zq = *(const int4*)(qz + (size_t)g * N_DIM + n0 + nl);
    const float4 sv = *(const float4*)(sc + (size_t)g * N_DIM + n0 + nl);
#pragma unroll
    for (int i = 0; i < 16; ++i) {
      const int kl = i * 4 + kb;
      const int4 q = *(const int4*)(qw + (size_t)(k0 + kl) * N_DIM + n0 + nl);
      w_lds[kl][nl + 0] = f2b((float)(q.x - zq.x) * sv.x);
      w_lds[kl][nl + 1] = f2b((float)(q.y - zq.y) * sv.y);
      w_lds[kl][nl + 2] = f2b((float)(q.z - zq.z) * sv.z);
      w_lds[kl][nl + 3] = f2b((float)(q.w - zq.w) * sv.w);
    }
    __syncthreads();
    const int c = tid & 7;          // k-chunk (8 k = 16B)
    const int ns = (tid >> 3) & 7;  // n-sub within wave
    const int w = tid >> 6;
#pragma unroll
    for (int v = 0; v < 8; ++v) {
      const int n = w * 64 + v * 8 + ns;
      unsigned short tmp[8];
#pragma unroll
      for (int i = 0; i < 8; ++i) tmp[i] = w_lds[c * 8 + i][n];
      *(uint4*)(Wt + (size_t)(n0 + n) * KP + k0 + c * 8) = *(const uint4*)tmp;
    }

  } else {
    // ---------------- lora_b^T into Wt cols [4096, 4160)
    unsigned short (*b_lds)[68] = (unsigned short (*)[68])smem;  // 8.7 KB
    const int n0 = (bid - NPX - NDQ) * 64;
    const int nl = tid & 63;
    const int rl0 = tid >> 6;
#pragma unroll
    for (int i = 0; i < 16; ++i) {
      const int rl = i * 4 + rl0;
      b_lds[nl][rl] = f2b(B[(size_t)rl * N_DIM + n0 + nl]);
    }
    __syncthreads();
#pragma unroll
    for (int p = 0; p < 2; ++p) {
      const int chunk = p * 256 + tid;
      const int nr = chunk >> 3, r8 = chunk & 7;
      const unsigned short* rp = &b_lds[nr][r8 * 8];
      const uint2 lo = *(const uint2*)rp;
      const uint2 hi = *(const uint2*)(rp + 4);
      uint4 v;
      v.x = lo.x; v.y = lo.y; v.z = hi.x; v.w = hi.y;
      *(uint4*)(Wt + (size_t)(n0 + nr) * KP + K_DIM + r8 * 8) = v;
    }
  }
}

// ---------------------------------------------------------------- main GEMM (r12, unchanged)
__global__ __launch_bounds__(512, 2) void gemm_kernel(
    const unsigned short* __restrict__ Xe, const unsigned short* __restrict__ Wt,
    float* __restrict__ out) {
  __shared__ unsigned short lds[2][2][2][128 * 64];
  const int tid = threadIdx.x;
  const int w = tid >> 6, lane = tid & 63;
  // T1: bijective XCD swizzle, 1376 = 8 * 172
  const int orig = blockIdx.x;
  const int wg = (orig & 7) * 172 + (orig >> 3);
  const int bm = wg & 31;   // 32 M-tiles
  const int bn = wg >> 5;   // 43 N-tiles
  const int wr = w >> 2, wc = w & 3;

  // staging: lane l writes phys chunk (l&7) of stripe-row w*8+(l>>3); source
  // logical chunk = (l&7) ^ sigma(row), sigma(row) = (row&7)^((row>>3)&3)
  const int rb = w * 8 + (lane >> 3);
  const int sc = ((lane & 7) ^ (lane >> 3) ^ (w & 3)) * 8;
  const unsigned short* gA = Xe + (size_t)(bm * 256 + rb) * KP + sc;
  const unsigned short* gB = Wt + (size_t)(bn * 256 + rb) * KP + sc;

  // fragment reads: row r = l&31 (+32 multiples), phys chunk =
  // logical ^ (l&7) ^ ((l>>3)&3) -- bank-spread (r7-verified, 0 conflicts)
  const int rowA32 = (lane & 31) * 64;
  const int rowB32 = ((wc & 1) * 64 + (lane & 31)) * 64;
  int cxk[4];
#pragma unroll
  for (int ks = 0; ks < 4; ++ks)
    cxk[ks] = ((ks * 2 + (lane >> 5)) ^ (lane & 7) ^ ((lane >> 3) & 3)) * 8;

  f32x16 acc[4][2];
#pragma unroll
  for (int i = 0; i < 4; ++i)
#pragma unroll
    for (int j = 0; j < 2; ++j) acc[i][j] = (f32x16)0.f;

  bf16x8 a[2][4], b0x[4], b0y[4], b1[4];

  // one gload_lds: rows [rq*64, rq*64+64) of region [op][half]
  auto stage1 = [&](const unsigned short* g, int buf, int op, int half, int rq,
                    int kt) {
    const unsigned short* s = g + (size_t)(half * 128 + rq * 64) * KP + kt * 64;
    unsigned short* d = &lds[buf][op][half][rq * 4096 + w * 512];
    GLOAD_LDS16(s, d);
  };

#define LDA(BUF, mh)                                                           \
  do {                                                                         \
    const unsigned short* R = &lds[BUF][0][wr][0];                             \
    _Pragma("unroll") for (int i = 0; i < 2; ++i)                              \
    _Pragma("unroll") for (int ks = 0; ks < 4; ++ks)                           \
      a[i][ks] =                                                               \
          *(const bf16x8*)(R + ((mh)*2 + i) * 2048 + rowA32 + cxk[ks]);        \
  } while (0)

#define LDB(BUF, dst, nh)                                                      \
  do {                                                                         \
    const unsigned short* R = &lds[BUF][1][wc >> 1][0];                        \
    _Pragma("unroll") for (int ks = 0; ks < 4; ++ks)                           \
      dst[ks] = *(const bf16x8*)(R + (nh)*2048 + rowB32 + cxk[ks]);            \
  } while (0)

#define MFMAQ(mh, bb, nh)                                                      \
  do {                                                                         \
    _Pragma("unroll") for (int ks = 0; ks < 4; ++ks)                           \
    _Pragma("unroll") for (int i = 0; i < 2; ++i)                              \
      acc[(mh)*2 + i][nh] = __builtin_amdgcn_mfma_f32_32x32x16_bf16(           \
          a[i][ks], bb[ks], acc[(mh)*2 + i][nh], 0, 0, 0);                     \
  } while (0)

#define LGKM0() do { asm volatile("s_waitcnt lgkmcnt(0)" ::: "memory"); SB0(); } while (0)
#define PRIO_ON()  __builtin_amdgcn_s_setprio(1)
#define PRIO_OFF() __builtin_amdgcn_s_setprio(0)
#define VM4() asm volatile("s_waitcnt vmcnt(4)" ::: "memory")
#define VM2() asm volatile("s_waitcnt vmcnt(2)" ::: "memory")
#define VM0() asm volatile("s_waitcnt vmcnt(0)" ::: "memory")
#define VNOP() ((void)0)

#define TILE(KT, BUF, CURB, NXTB, S1, S2, VMA, VMB, LAST)                      \
  do {                                                                         \
    const int kt_ = (KT);                                                      \
    /* I1: 8 MFMA | 4 ds_read | 2 vmem */                                      \
    LGKM0();                                                                   \
    PRIO_ON(); MFMAQ(0, CURB, 0);                                              \
    LDB(BUF, b1, 1);                                                           \
    PRIO_OFF();                                                                \
    if (S1) { stage1(gA, (BUF) ^ 1, 0, 0, 0, kt_ + 1);                         \
              stage1(gA, (BUF) ^ 1, 0, 1, 0, kt_ + 1); }                       \
    ILV(4, (S1) ? 2 : 0);                                                      \
    SB0(); BAR(); SB0();                                                       \
    /* I2: 8 MFMA | 8 ds_read | 2 vmem */                                      \
    LGKM0();                                                                   \
    PRIO_ON(); MFMAQ(0, b1, 1);                                                \
    LDA(BUF, 1);                                                               \
    PRIO_OFF();                                                                \
    if (S1) { stage1(gA, (BUF) ^ 1, 0, 0, 1, kt_ + 1);                         \
              stage1(gA, (BUF) ^ 1, 0, 1, 1, kt_ + 1); }                       \
    ILV(8, (S1) ? 2 : 0);                                                      \
    SB0(); VMA(); SB0(); BAR(); SB0();                                         \
    /* I3: 8 MFMA | 4 ds_read | 2 vmem */                                      \
    LGKM0();                                                                   \
    PRIO_ON(); MFMAQ(1, b1, 1);                                                \
    if (!(LAST)) { LDB((BUF) ^ 1, NXTB, 0); }                                  \
    PRIO_OFF();                                                                \
    if (S2) { stage1(gB, (BUF), 1, 0, 0, kt_ + 2);                             \
              stage1(gB, (BUF), 1, 1, 0, kt_ + 2); }                           \
    ILV((LAST) ? 0 : 4, (S2) ? 2 : 0);                                         \
    SB0(); VMB(); SB0(); BAR(); SB0();                                         \
    /* I4: 8 MFMA | 8 ds_read | 2 vmem */                                      \
    LGKM0();                                                                   \
    PRIO_ON(); MFMAQ(1, CURB, 0);                                              \
    if (!(LAST)) { LDA((BUF) ^ 1, 0); }                                        \
    PRIO_OFF();                                                                \
    if (S2) { stage1(gB, (BUF), 1, 0, 1, kt_ + 2);                             \
              stage1(gB, (BUF), 1, 1, 1, kt_ + 2); }                           \
    ILV((LAST) ? 0 : 8, (S2) ? 2 : 0);                                         \
    SB0(); BAR(); SB0();                                                       \
  } while (0)

  // prologue: stage A(0) q0,q1 (4), B(0) (4), B(1) (4); vmcnt(4) -> tile0
  // landed, B(1) in flight; then initial fragment reads.
  stage1(gA, 0, 0, 0, 0, 0); stage1(gA, 0, 0, 1, 0, 0);
  stage1(gA, 0, 0, 0, 1, 0); stage1(gA, 0, 0, 1, 1, 0);
  stage1(gB, 0, 1, 0, 0, 0); stage1(gB, 0, 1, 1, 0, 0);
  stage1(gB, 0, 1, 0, 1, 0); stage1(gB, 0, 1, 1, 1, 0);
  stage1(gB, 1, 1, 0, 0, 1); stage1(gB, 1, 1, 1, 0, 1);
  stage1(gB, 1, 1, 0, 1, 1); stage1(gB, 1, 1, 1, 1, 1);
  SB0(); VM4(); SB0(); BAR(); SB0();
  LDA(0, 0);          // a = mh0(0)
  LDB(0, b0x, 0);     // b0x = B(0) n0   (awaited by tile0 I1's LGKM0)

#pragma unroll 1
  for (int kt = 0; kt < 62; kt += 2) {
    TILE(kt,     0, b0x, b0y, true, true, VM4, VM2, false);
    TILE(kt + 1, 1, b0y, b0x, true, true, VM4, VM2, false);
  }
  TILE(62, 0, b0x, b0y, true,  true,  VM4,  VM2,  false);
  TILE(63, 1, b0y, b0x, true,  false, VM4,  VM0,  false);
  TILE(64, 0, b0x, b0y, false, false, VNOP, VNOP, true);

  // epilogue: 32x32 C/D layout: col = lane&31, row = (reg&3)+8*(reg>>2)+4*(lane>>5)
  const int orow = bm * 256 + wr * 128 + ((lane >> 5) << 2);
  const int ocol = bn * 256 + wc * 64 + (lane & 31);
#pragma unroll
  for (int mf = 0; mf < 4; ++mf)
#pragma unroll
    for (int nf = 0; nf < 2; ++nf)
#pragma unroll
      for (int reg = 0; reg < 16; ++reg)
        out[(size_t)(orow + mf * 32 + (reg & 3) + ((reg >> 2) << 3)) * N_DIM +
            ocol + nf * 32] = acc[mf][nf][reg];
}

// ---------------------------------------------------------------- launch
extern "C" void kernel_launch(void* const* d_in, const int* in_sizes, int n_in,
                              void* d_out, int out_size, void* d_ws, size_t ws_size,
                              hipStream_t stream) {
  const float* x = (const float*)d_in[0];
  const float* scales = (const float*)d_in[1];
  const float* lora_a = (const float*)d_in[2];
  const float* lora_b = (const float*)d_in[3];
  const int* qweight = (const int*)d_in[4];
  const int* qzeros = (const int*)d_in[5];
  float* out = (float*)d_out;

  unsigned short* Xe = (unsigned short*)d_ws;
  unsigned short* Wt = Xe + (size_t)M_DIM * KP;

  prep_all_kernel<<<NPX + NDQ + NLB, 256, 0, stream>>>(
      x, lora_a, lora_b, qweight, qzeros, scales, Xe, Wt);
  gemm_kernel<<<dim3((N_DIM / 256) * (M_DIM / 256)), 512, 0, stream>>>(Xe, Wt, out);
}